// Round 7
// baseline (3235.752 us; speedup 1.0000x reference)
//
#include <hip/hip_runtime.h>
#include <cstddef>
#include <cstdint>

// ============================================================================
// GraphPropagationBlock on MI355X — all-fp32 implementation (round 7).
// Identical logic to round 6 (which never ran: GPU acquisition timeout).
// Round-6/7 deltas vs round 5 (which core-dumped at first launch):
//   * Workspace shrunk 323MB -> 234.6MiB (suspected ws_size overflow -> GPU
//     memory fault). QKV split into QK (dies at qk_kernel) + V (dies at
//     av_kernel); AOUT/XRES/H2 alias the QK region, wbuf aliases V.
//   * Defensive clamps on kept/elim consumers: pathological selection now
//     yields a wrong answer (absmax feedback) instead of an OOB fault.
// Third full audit this round: bounds, alias lifetimes, float4 alignment,
// reference semantics (stable argsort, radix-select ties, pagerank skip,
// GELU erf, output concat) — all verified.
// ============================================================================

#define DEV_INLINE __device__ __forceinline__

DEV_INLINE float waveReduceSum(float v) {
#pragma unroll
  for (int off = 32; off > 0; off >>= 1) v += __shfl_xor(v, off, 64);
  return v;
}
DEV_INLINE float waveReduceMax(float v) {
#pragma unroll
  for (int off = 32; off > 0; off >>= 1) v = fmaxf(v, __shfl_xor(v, off, 64));
  return v;
}
DEV_INLINE int clampi(int v, int lo, int hi) { return v < lo ? lo : (v > hi ? hi : v); }

// ---------------------------------------------------------------------------
// LayerNorm over C=768, one block (256 thr) per row, 3 elems/thread. (LN1)
// ---------------------------------------------------------------------------
__global__ __launch_bounds__(256) void ln_kernel(
    const float* __restrict__ x, const float* __restrict__ g,
    const float* __restrict__ bb, float* __restrict__ y)
{
  const int row = blockIdx.x;
  const int t = threadIdx.x;
  const float* xr = x + (size_t)row * 768;
  float* yr = y + (size_t)row * 768;
  float v0 = xr[t], v1 = xr[t + 256], v2 = xr[t + 512];
  __shared__ float red[8];
  const int wid = t >> 6, lane = t & 63;
  float s = v0 + v1 + v2;
  s = waveReduceSum(s);
  if (lane == 0) red[wid] = s;
  __syncthreads();
  if (t == 0) red[4] = (red[0] + red[1] + red[2] + red[3]) * (1.f / 768.f);
  __syncthreads();
  const float mu = red[4];
  float d0 = v0 - mu, d1 = v1 - mu, d2 = v2 - mu;
  float q = d0 * d0 + d1 * d1 + d2 * d2;
  q = waveReduceSum(q);
  if (lane == 0) red[wid] = q;
  __syncthreads();
  if (t == 0) red[5] = 1.0f / sqrtf((red[0] + red[1] + red[2] + red[3]) * (1.f / 768.f) + 1e-5f);
  __syncthreads();
  const float rs = red[5];
  yr[t]       = d0 * rs * g[t]       + bb[t];
  yr[t + 256] = d1 * rs * g[t + 256] + bb[t + 256];
  yr[t + 512] = d2 * rs * g[t + 512] + bb[t + 512];
}

// ---------------------------------------------------------------------------
// Generic fp32 GEMM: C[M,N] = A[M,K] @ B[N,K]^T (+bias) (+GELU) (+residual).
// BM=64, BN=128, BK=16; 128 threads; 8x8 per thread (split fragments:
// rows {r0..r0+3, r0+32..}, cols {c0..c0+3, c0+64..}); double-buffered LDS.
// All fragment reads 16B-stride (2 lanes/bank = free); staging writes 2-way.
// Requires M%64==0, N%128==0, K%16==0 (true for all call sites).
// grid = (M/64, N/128)
// ---------------------------------------------------------------------------
__global__ __launch_bounds__(128) void gemm_bias_act(
    const float* __restrict__ A, int lda,
    const float* __restrict__ B, int ldb,
    const float* __restrict__ bias,   // may be null
    const float* __restrict__ res,    // may be null (same layout as C)
    float* __restrict__ C, int ldc,
    int K, int act)
{
  __shared__ float As[2][16][68];   // [buf][k][m]
  __shared__ float Bs[2][16][132];  // [buf][k][n]
  const int t = threadIdx.x;
  const int m0 = blockIdx.x * 64;
  const int n0 = blockIdx.y * 128;

  const int sar = t >> 1;
  const int sak = (t & 1) << 3;
  const float* Aptr = A + (size_t)(m0 + sar) * lda + sak;
  const float* Bptr = B + (size_t)(n0 + t) * ldb;

  const int r0 = (t >> 4) << 2;   // 0..28
  const int c0 = (t & 15) << 2;   // 0..60

  float acc[8][8];
#pragma unroll
  for (int i = 0; i < 8; ++i)
#pragma unroll
    for (int j = 0; j < 8; ++j) acc[i][j] = 0.f;

  float4 a0 = *(const float4*)(Aptr);
  float4 a1 = *(const float4*)(Aptr + 4);
  float4 b0 = *(const float4*)(Bptr);
  float4 b1 = *(const float4*)(Bptr + 4);
  float4 b2 = *(const float4*)(Bptr + 8);
  float4 b3 = *(const float4*)(Bptr + 12);

  int buf = 0;
  for (int k0 = 0; k0 < K; k0 += 16) {
    As[buf][sak + 0][sar] = a0.x; As[buf][sak + 1][sar] = a0.y;
    As[buf][sak + 2][sar] = a0.z; As[buf][sak + 3][sar] = a0.w;
    As[buf][sak + 4][sar] = a1.x; As[buf][sak + 5][sar] = a1.y;
    As[buf][sak + 6][sar] = a1.z; As[buf][sak + 7][sar] = a1.w;
    Bs[buf][ 0][t] = b0.x; Bs[buf][ 1][t] = b0.y;
    Bs[buf][ 2][t] = b0.z; Bs[buf][ 3][t] = b0.w;
    Bs[buf][ 4][t] = b1.x; Bs[buf][ 5][t] = b1.y;
    Bs[buf][ 6][t] = b1.z; Bs[buf][ 7][t] = b1.w;
    Bs[buf][ 8][t] = b2.x; Bs[buf][ 9][t] = b2.y;
    Bs[buf][10][t] = b2.z; Bs[buf][11][t] = b2.w;
    Bs[buf][12][t] = b3.x; Bs[buf][13][t] = b3.y;
    Bs[buf][14][t] = b3.z; Bs[buf][15][t] = b3.w;
    __syncthreads();
    if (k0 + 16 < K) {  // prefetch next slab; latency hides under compute
      a0 = *(const float4*)(Aptr + k0 + 16);
      a1 = *(const float4*)(Aptr + k0 + 20);
      b0 = *(const float4*)(Bptr + k0 + 16);
      b1 = *(const float4*)(Bptr + k0 + 20);
      b2 = *(const float4*)(Bptr + k0 + 24);
      b3 = *(const float4*)(Bptr + k0 + 28);
    }
#pragma unroll
    for (int kk = 0; kk < 16; ++kk) {
      float4 av0 = *(const float4*)&As[buf][kk][r0];
      float4 av1 = *(const float4*)&As[buf][kk][r0 + 32];
      float4 bv0 = *(const float4*)&Bs[buf][kk][c0];
      float4 bv1 = *(const float4*)&Bs[buf][kk][c0 + 64];
      float ar[8] = {av0.x, av0.y, av0.z, av0.w, av1.x, av1.y, av1.z, av1.w};
      float br[8] = {bv0.x, bv0.y, bv0.z, bv0.w, bv1.x, bv1.y, bv1.z, bv1.w};
#pragma unroll
      for (int i = 0; i < 8; ++i)
#pragma unroll
        for (int j = 0; j < 8; ++j) acc[i][j] = fmaf(ar[i], br[j], acc[i][j]);
    }
    buf ^= 1;
  }

#pragma unroll
  for (int i = 0; i < 8; ++i) {
    const int m = m0 + ((i < 4) ? (r0 + i) : (32 + r0 + i - 4));
    float* Crow = C + (size_t)m * ldc + n0;
    const float* Rrow = res ? res + (size_t)m * ldc + n0 : nullptr;
#pragma unroll
    for (int j = 0; j < 8; ++j) {
      const int n = (j < 4) ? (c0 + j) : (64 + c0 + j - 4);
      float v = acc[i][j];
      if (bias) v += bias[n0 + n];
      if (act == 1) v = 0.5f * v * (1.f + erff(v * 0.70710678118654752440f));
      if (Rrow) v += Rrow[n];
      Crow[n] = v;
    }
  }
}

// ---------------------------------------------------------------------------
// QK^T per (b,h): logits[n,m] = (0.125*q[n]) . k[m]. grid (4, 2, B*H).
// qk buffer layout: row (b*197+n), col = which*768 + h*64 + d, ld = 1536
// (which: 0=Q, 1=K). Split-fragment columns for conflict-free LDS.
// ---------------------------------------------------------------------------
__global__ __launch_bounds__(256) void qk_kernel(
    const float* __restrict__ qk, float* __restrict__ attn)
{
  const int bh = blockIdx.z;
  const int b = bh / 12, h = bh % 12;
  const int n0 = blockIdx.x * 64;
  const int m0 = blockIdx.y * 128;
  __shared__ float Qs[16][68];
  __shared__ float Ks[16][132];
  const int t = threadIdx.x;
  const int lr = t >> 2;
  const int lk = (t & 3) << 2;
  const float* base = qk + (size_t)b * 197 * 1536 + h * 64;
  float acc[4][8];
#pragma unroll
  for (int i = 0; i < 4; ++i)
#pragma unroll
    for (int j = 0; j < 8; ++j) acc[i][j] = 0.f;
  const int r0 = (t >> 4) << 2;
  const int c0 = (t & 15) << 2;

  for (int k0 = 0; k0 < 64; k0 += 16) {
    const int n = n0 + lr;
    float4 av = make_float4(0.f, 0.f, 0.f, 0.f);
    if (n < 197) av = *(const float4*)(base + (size_t)n * 1536 + k0 + lk);
    av.x *= 0.125f; av.y *= 0.125f; av.z *= 0.125f; av.w *= 0.125f;
    const int m1 = m0 + lr, m2 = m0 + 64 + lr;
    float4 bv0 = make_float4(0.f, 0.f, 0.f, 0.f);
    float4 bv1 = make_float4(0.f, 0.f, 0.f, 0.f);
    if (m1 < 197) bv0 = *(const float4*)(base + 768 + (size_t)m1 * 1536 + k0 + lk);
    if (m2 < 197) bv1 = *(const float4*)(base + 768 + (size_t)m2 * 1536 + k0 + lk);
    Qs[lk + 0][lr] = av.x;  Qs[lk + 1][lr] = av.y;
    Qs[lk + 2][lr] = av.z;  Qs[lk + 3][lr] = av.w;
    Ks[lk + 0][lr] = bv0.x; Ks[lk + 1][lr] = bv0.y;
    Ks[lk + 2][lr] = bv0.z; Ks[lk + 3][lr] = bv0.w;
    Ks[lk + 0][lr + 64] = bv1.x; Ks[lk + 1][lr + 64] = bv1.y;
    Ks[lk + 2][lr + 64] = bv1.z; Ks[lk + 3][lr + 64] = bv1.w;
    __syncthreads();
#pragma unroll
    for (int kk = 0; kk < 16; ++kk) {
      float4 a  = *(const float4*)&Qs[kk][r0];
      float4 b0 = *(const float4*)&Ks[kk][c0];
      float4 b1 = *(const float4*)&Ks[kk][c0 + 64];
      float ar[4] = {a.x, a.y, a.z, a.w};
      float br[8] = {b0.x, b0.y, b0.z, b0.w, b1.x, b1.y, b1.z, b1.w};
#pragma unroll
      for (int i = 0; i < 4; ++i)
#pragma unroll
        for (int j = 0; j < 8; ++j) acc[i][j] = fmaf(ar[i], br[j], acc[i][j]);
    }
    __syncthreads();
  }

  float* ab = attn + (size_t)bh * 38809;
#pragma unroll
  for (int i = 0; i < 4; ++i) {
    const int n = n0 + r0 + i;
    if (n >= 197) continue;
#pragma unroll
    for (int j = 0; j < 8; ++j) {
      const int m = m0 + ((j < 4) ? (c0 + j) : (64 + c0 + j - 4));
      if (m < 197) ab[(size_t)n * 197 + m] = acc[i][j];
    }
  }
}

// ---------------------------------------------------------------------------
// Fused softmax (+log token_scales bias) + head-mean + rowsum.
// One block per (b,n): wave wid handles heads {wid, wid+4, wid+8}.
// Writes attn in place, wm[b,n,:], rowsum[b,n-1] = sum_{m>=1} wm.
// grid = B*197 = 12608 blocks, 256 threads.
// ---------------------------------------------------------------------------
__global__ __launch_bounds__(256) void softmax_fused(
    float* __restrict__ attn, const float* __restrict__ ts,
    float* __restrict__ wm, float* __restrict__ rowsum)
{
  const int bn = blockIdx.x;
  const int b = bn / 197, n = bn % 197;
  const int t = threadIdx.x;
  const int wid = t >> 6, lane = t & 63;
  __shared__ float colbuf[200];     // logts, then reused for wm row
  __shared__ float hsum[4][200];
  if (t < 197) colbuf[t] = logf(ts[b * 197 + t]);
  __syncthreads();

  int mm[4]; bool val[4];
#pragma unroll
  for (int i = 0; i < 4; ++i) { mm[i] = lane + 64 * i; val[i] = mm[i] < 197; }
  float lts[4];
#pragma unroll
  for (int i = 0; i < 4; ++i) lts[i] = val[i] ? colbuf[mm[i]] : 0.f;

  float macc[4] = {0.f, 0.f, 0.f, 0.f};
  for (int hi = 0; hi < 3; ++hi) {
    const int h = wid + 4 * hi;
    float* p = attn + ((size_t)(b * 12 + h) * 197 + n) * 197;
    float v[4];
#pragma unroll
    for (int i = 0; i < 4; ++i)
      v[i] = val[i] ? p[mm[i]] + lts[i] : -3.4e38f;
    float mx = waveReduceMax(fmaxf(fmaxf(v[0], v[1]), fmaxf(v[2], v[3])));
    float e[4]; float s = 0.f;
#pragma unroll
    for (int i = 0; i < 4; ++i) { e[i] = val[i] ? expf(v[i] - mx) : 0.f; s += e[i]; }
    s = waveReduceSum(s);
    const float inv = 1.f / s;
#pragma unroll
    for (int i = 0; i < 4; ++i) {
      if (val[i]) { const float a = e[i] * inv; p[mm[i]] = a; macc[i] += a; }
    }
  }
#pragma unroll
  for (int i = 0; i < 4; ++i) if (val[i]) hsum[wid][mm[i]] = macc[i];
  __syncthreads();
  if (t < 197) {
    const float wmv = (hsum[0][t] + hsum[1][t] + hsum[2][t] + hsum[3][t]) * (1.f / 12.f);
    wm[(size_t)b * 38809 + (size_t)n * 197 + t] = wmv;
    colbuf[t] = wmv;
  }
  __syncthreads();
  if (n >= 1 && wid == 0) {
    float s = colbuf[1 + lane] + colbuf[65 + lane] + colbuf[129 + lane];
    if (lane < 4) s += colbuf[193 + lane];
    s = waveReduceSum(s);
    if (lane == 0) rowsum[b * 196 + (n - 1)] = s;
  }
}

// ---------------------------------------------------------------------------
// attn @ V per (b,h): out[n,d] written into [B,N,C] at col h*64+d.
// V buffer: [B*197, 768] (col h*64+d). grid (4, B*H). BM=64 x BN=64, BK=16.
// ---------------------------------------------------------------------------
__global__ __launch_bounds__(256) void av_kernel(
    const float* __restrict__ v, const float* __restrict__ attn,
    float* __restrict__ aout)
{
  const int bh = blockIdx.y;
  const int b = bh / 12, h = bh % 12;
  const int n0 = blockIdx.x * 64;
  __shared__ float Ps[16][68];
  __shared__ float Vs[16][68];
  const int t = threadIdx.x;
  const float* ab = attn + (size_t)bh * 38809;
  const float* vbase = v + (size_t)b * 197 * 768 + h * 64;
  float acc[4][4];
#pragma unroll
  for (int i = 0; i < 4; ++i)
#pragma unroll
    for (int j = 0; j < 4; ++j) acc[i][j] = 0.f;
  const int r0 = (t >> 4) << 2;  // n
  const int c0 = (t & 15) << 2;  // d

  for (int k0 = 0; k0 < 197; k0 += 16) {
    {
      const int kk = t & 15;
      const int nb = t >> 4;
#pragma unroll
      for (int s = 0; s < 4; ++s) {
        const int n = nb + 16 * s;
        const int gn = n0 + n, gk = k0 + kk;
        float vv = 0.f;
        if (gn < 197 && gk < 197) vv = ab[(size_t)gn * 197 + gk];
        Ps[kk][n] = vv;
      }
      const int d = t & 63;
      const int kb = t >> 6;
#pragma unroll
      for (int s = 0; s < 4; ++s) {
        const int kk2 = kb + 4 * s;
        const int gk = k0 + kk2;
        float vv = 0.f;
        if (gk < 197) vv = vbase[(size_t)gk * 768 + d];
        Vs[kk2][d] = vv;
      }
    }
    __syncthreads();
#pragma unroll
    for (int kk = 0; kk < 16; ++kk) {
      float4 a = *(const float4*)&Ps[kk][r0];
      float4 bv = *(const float4*)&Vs[kk][c0];
      float ar[4] = {a.x, a.y, a.z, a.w};
      float br[4] = {bv.x, bv.y, bv.z, bv.w};
#pragma unroll
      for (int i = 0; i < 4; ++i)
#pragma unroll
        for (int j = 0; j < 4; ++j) acc[i][j] = fmaf(ar[i], br[j], acc[i][j]);
    }
    __syncthreads();
  }

#pragma unroll
  for (int i = 0; i < 4; ++i) {
    const int n = n0 + r0 + i;
    if (n >= 197) continue;
#pragma unroll
    for (int j = 0; j < 4; ++j)
      aout[((size_t)b * 197 + n) * 768 + h * 64 + c0 + j] = acc[i][j];
  }
}

// init pr0 = 1/196 and dist2[0..19] = 0
__global__ __launch_bounds__(256) void init_pr(
    float* __restrict__ prA, float* __restrict__ dist2)
{
  const int i = blockIdx.x * 256 + threadIdx.x;
  if (i < 12544) prA[i] = 1.f / 196.f;
  if (i < 20) dist2[i] = 0.f;
}

// one pagerank iteration, split 2 blocks per batch: grid (64, 2) x 128 thr.
// Block (b,half) computes output rows half*98..half*98+97. Kernel j skips
// (copying its rows) iff dist2[j-1] < 1e-6 (while cond: dist >= 1e-3).
__global__ __launch_bounds__(128) void pagerank_iter(
    const float* __restrict__ wm, const float* __restrict__ rowsum,
    const float* __restrict__ prIn, float* __restrict__ prOut,
    float* __restrict__ dist2, int j)
{
  const int b = blockIdx.x, half = blockIdx.y, t = threadIdx.x;
  const int row = half * 98 + t;  // t < 98 active
  if (j > 0 && dist2[j - 1] < 1e-6f) {
    if (t < 98) prOut[b * 196 + row] = prIn[b * 196 + row];
    return;
  }
  __shared__ float u[196];
  for (int i = t; i < 196; i += 128) u[i] = prIn[b * 196 + i] / rowsum[b * 196 + i];
  __syncthreads();
  float d2 = 0.f;
  if (t < 98) {
    const float* base = wm + (size_t)b * 38809 + 1 + row;
    float a0 = 0.f, a1 = 0.f, a2 = 0.f, a3 = 0.f;
    for (int c = 0; c < 196; c += 4) {
      a0 = fmaf(base[(size_t)(1 + c) * 197], u[c], a0);
      a1 = fmaf(base[(size_t)(2 + c) * 197], u[c + 1], a1);
      a2 = fmaf(base[(size_t)(3 + c) * 197], u[c + 2], a2);
      a3 = fmaf(base[(size_t)(4 + c) * 197], u[c + 3], a3);
    }
    const float acc = (a0 + a1) + (a2 + a3);
    const float nw = 0.95f * acc + (0.05f / 196.f);
    const float d = nw - prIn[b * 196 + row];
    d2 = d * d;
    prOut[b * 196 + row] = nw;
  }
  d2 = waveReduceSum(d2);
  __shared__ float red[2];
  if ((t & 63) == 0) red[t >> 6] = d2;
  __syncthreads();
  if (t == 0) atomicAdd(&dist2[j], red[0] + red[1]);
}

// ---------------------------------------------------------------------------
// Selection: stable descending argsort by rank counting; build sorted
// kept (CLS + top98 tokens, ascending) and elim lists + gathered scales.
// Writes are clamped (defensive: pathological pr -> wrong answer, not OOB).
// ---------------------------------------------------------------------------
__global__ __launch_bounds__(256) void select_kernel(
    const float* __restrict__ pr, const float* __restrict__ ts,
    int* __restrict__ kept, int* __restrict__ elim,
    float* __restrict__ tsk, float* __restrict__ tse)
{
  const int b = blockIdx.x, t = threadIdx.x;
  __shared__ float v[196];
  __shared__ unsigned char kf[196];
  if (t < 196) v[t] = pr[b * 196 + t];
  __syncthreads();
  if (t < 196) {
    const float vt = v[t];
    int rank = 0;
    for (int j = 0; j < 196; ++j) {
      const float vj = v[j];
      rank += (vj > vt) || (vj == vt && j < t);
    }
    kf[t] = (rank < 98) ? 1 : 0;
  }
  __syncthreads();
  if (t < 196) {
    int pos = 0;
    for (int j = 0; j < t; ++j) pos += kf[j];
    const int tok = t + 1;
    if (kf[t]) {
      const int p2 = clampi(pos, 0, 97);
      kept[b * 99 + 1 + p2] = tok;
      tsk[b * 99 + 1 + p2] = ts[b * 197 + tok];
    } else {
      const int e2 = clampi(t - pos, 0, 97);
      elim[b * 98 + e2] = tok;
      tse[b * 98 + e2] = ts[b * 197 + tok];
    }
  }
  if (t == 0) { kept[b * 99] = 0; tsk[b * 99] = ts[b * 197]; }
}

// gather w[b,h,k,e] = attn[b,h,kept[k],elim[e]]  grid (38, B*H)
__global__ __launch_bounds__(256) void gather_w(
    const float* __restrict__ attn, const int* __restrict__ kept,
    const int* __restrict__ elim, float* __restrict__ wbuf)
{
  const int bh = blockIdx.y;
  const int b = bh / 12;
  const float* ab = attn + (size_t)bh * 38809;
  const int* kb = kept + b * 99;
  const int* eb = elim + b * 98;
  float* wb = wbuf + (size_t)bh * 9702;
  const int i = blockIdx.x * 256 + threadIdx.x;
  if (i < 9702) {
    const int k = i / 98, e = i % 98;
    const int kt = clampi(kb[k], 0, 196);
    const int et = clampi(eb[e], 0, 196);
    wb[i] = ab[(size_t)kt * 197 + et];
  }
}

// per-(b,h) kth-largest (kth = int(9702*0.2)=1940, 0-indexed desc) via
// 4-pass radix select on positive-float bits. grid B*H blocks.
__global__ __launch_bounds__(256) void thresh_kernel(
    const float* __restrict__ wbuf, float* __restrict__ thr)
{
  const int bh = blockIdx.x, t = threadIdx.x;
  const float* wb = wbuf + (size_t)bh * 9702;
  __shared__ unsigned hist[256];
  __shared__ unsigned s_prefix;
  __shared__ int s_k;
  if (t == 0) { s_prefix = 0u; s_k = 1940; }
  for (int pass = 0; pass < 4; ++pass) {
    const int shift = 24 - 8 * pass;
    hist[t] = 0u;
    __syncthreads();
    const unsigned pref = s_prefix;
    for (int i = t; i < 9702; i += 256) {
      const unsigned u = __float_as_uint(wb[i]);
      const bool match = (pass == 0) || ((u >> (shift + 8)) == (pref >> (shift + 8)));
      if (match) atomicAdd(&hist[(u >> shift) & 255u], 1u);
    }
    __syncthreads();
    if (t == 0) {
      int k = s_k;
      int sel = 0;
      for (int bin = 255; bin >= 0; --bin) {
        const int c = (int)hist[bin];
        if (k < c) { sel = bin; break; }
        k -= c;
      }
      s_prefix |= ((unsigned)sel << shift);
      s_k = k;
    }
    __syncthreads();
  }
  if (t == 0) thr[bh] = __uint_as_float(s_prefix);
}

// x_prop[b,k,h*64+d] = sum_e wsp[k,e] * (x_res[b,elim[e],h*64+d]*tse[e])
// Also emits partial[bh*99+k] = sum_e wsp[k,e]*tse[e] (lane d==0 writes).
// grid B*H blocks, 256 thr (d = t&63, row group r = t>>6).
__global__ __launch_bounds__(256) void xprop_kernel(
    const float* __restrict__ xres, const float* __restrict__ wbuf,
    const float* __restrict__ thr, const int* __restrict__ elim,
    const float* __restrict__ tse, float* __restrict__ xprop,
    float* __restrict__ partial)
{
  const int bh = blockIdx.x;
  const int b = bh / 12, h = bh % 12;
  __shared__ float xe[98][68];
  __shared__ float tsew[98];
  const int t = threadIdx.x;
  const int d = t & 63, r = t >> 6;
  if (t < 98) tsew[t] = tse[b * 98 + t];
  for (int e = r; e < 98; e += 4) {
    const int tok = clampi(elim[b * 98 + e], 0, 196);
    xe[e][d] = xres[((size_t)b * 197 + tok) * 768 + h * 64 + d] * tse[b * 98 + e];
  }
  __syncthreads();
  const float th = thr[bh];
  const float* wb = wbuf + (size_t)bh * 9702;
  for (int k = r; k < 99; k += 4) {
    const float* wr = wb + k * 98;
    float acc = 0.f;
    float ssum = 0.f;
    for (int e = 0; e < 98; ++e) {
      float w = wr[e];
      w = (w >= th) ? w : 0.f;
      acc = fmaf(w, xe[e][d], acc);
      ssum = fmaf(w, tsew[e], ssum);
    }
    xprop[((size_t)b * 99 + k) * 768 + h * 64 + d] = acc;
    if (d == 0) partial[(size_t)bh * 99 + k] = ssum;
  }
}

// tsn[b,k] = tsk[b,k] + (1/12) sum_h partial[(b*12+h)*99+k]; writes out_ts.
// grid 25 x 256 (6336 items).
__global__ __launch_bounds__(256) void tsfinal_kernel(
    const float* __restrict__ partial, const float* __restrict__ tsk,
    float* __restrict__ tsn, float* __restrict__ out_ts)
{
  const int i = blockIdx.x * 256 + threadIdx.x;
  if (i >= 6336) return;
  const int b = i / 99, k = i % 99;
  float acc = 0.f;
#pragma unroll
  for (int h = 0; h < 12; ++h) acc += partial[(size_t)(b * 12 + h) * 99 + k];
  const float v = tsk[i] + acc * (1.f / 12.f);
  tsn[i] = v;
  out_ts[i] = v;
}

// ---------------------------------------------------------------------------
// Fused combine + LN2: per row bk, v = (x_res[kept]*tsk + xprop)/tsn is
// written to xout (needed for final residual) and layer-normed into y.
// grid 6336 blocks x 256 thr (3 elems/thread).
// ---------------------------------------------------------------------------
__global__ __launch_bounds__(256) void combine_ln_kernel(
    const float* __restrict__ xres, const float* __restrict__ xprop,
    const int* __restrict__ kept, const float* __restrict__ tsk,
    const float* __restrict__ tsn, const float* __restrict__ g,
    const float* __restrict__ bb, float* __restrict__ xout,
    float* __restrict__ y)
{
  const int bk = blockIdx.x;
  const int b = bk / 99;
  const int t = threadIdx.x;
  const int tok = clampi(kept[bk], 0, 196);
  const float sk = tsk[bk];
  const float sn = tsn[bk];
  const float* xr = xres + ((size_t)b * 197 + tok) * 768;
  const float* xp = xprop + (size_t)bk * 768;
  float v0 = (xr[t] * sk + xp[t]) / sn;
  float v1 = (xr[t + 256] * sk + xp[t + 256]) / sn;
  float v2 = (xr[t + 512] * sk + xp[t + 512]) / sn;
  float* xo = xout + (size_t)bk * 768;
  xo[t] = v0; xo[t + 256] = v1; xo[t + 512] = v2;

  __shared__ float red[8];
  const int wid = t >> 6, lane = t & 63;
  float s = v0 + v1 + v2;
  s = waveReduceSum(s);
  if (lane == 0) red[wid] = s;
  __syncthreads();
  if (t == 0) red[4] = (red[0] + red[1] + red[2] + red[3]) * (1.f / 768.f);
  __syncthreads();
  const float mu = red[4];
  float d0 = v0 - mu, d1 = v1 - mu, d2 = v2 - mu;
  float q = d0 * d0 + d1 * d1 + d2 * d2;
  q = waveReduceSum(q);
  if (lane == 0) red[wid] = q;
  __syncthreads();
  if (t == 0) red[5] = 1.0f / sqrtf((red[0] + red[1] + red[2] + red[3]) * (1.f / 768.f) + 1e-5f);
  __syncthreads();
  const float rs = red[5];
  float* yr = y + (size_t)bk * 768;
  yr[t]       = d0 * rs * g[t]       + bb[t];
  yr[t + 256] = d1 * rs * g[t + 256] + bb[t + 256];
  yr[t + 512] = d2 * rs * g[t + 512] + bb[t + 512];
}

// ============================================================================
extern "C" void kernel_launch(void* const* d_in, const int* in_sizes, int n_in,
                              void* d_out, int out_size, void* d_ws, size_t ws_size,
                              hipStream_t stream)
{
  const float* x      = (const float*)d_in[0];
  const float* ts     = (const float*)d_in[1];
  const float* w_qkv  = (const float*)d_in[2];
  const float* w_proj = (const float*)d_in[3];
  const float* b_proj = (const float*)d_in[4];
  const float* ln1_g  = (const float*)d_in[5];
  const float* ln1_b  = (const float*)d_in[6];
  const float* ln2_g  = (const float*)d_in[7];
  const float* ln2_b  = (const float*)d_in[8];
  const float* w_fc1  = (const float*)d_in[9];
  const float* b_fc1  = (const float*)d_in[10];
  const float* w_fc2  = (const float*)d_in[11];
  const float* b_fc2  = (const float*)d_in[12];
  float* out = (float*)d_out;
  float* ws  = (float*)d_ws;

  // -------- workspace layout: 61,483,936 floats = 234.6 MiB --------
  // R_QK   [19,365,888]: QK (qkvGEMM->qk_kernel); then AOUT@+0 (av->proj),
  //                      XRES@+9,682,944 (proj->xprop/combine), H2@+0
  //                      (combine_ln->fc1; disjoint from live XRES).
  // R_V    [ 9,682,944]: V (qkvGEMM->av); then WBUF@+0 (gather->xprop).
  // R_ATTN [29,805,312]: H1@+0 (ln1->qkvGEMMs); ATTN (qk->gather_w); then
  //                      XPROP@+0, XOUT@+4,866,048, HBUF@+9,732,096.
  // R_WM   [ 2,483,776]: head-mean (softmax_fused->pagerank).
  const size_t O_QK     = 0;
  const size_t O_V      = 19365888;
  const size_t O_ATTNR  = 29048832;
  const size_t O_WM     = 58854144;
  const size_t O_ROWSUM = 61337920;   // 12,544
  const size_t O_PRA    = 61350464;   // 12,544
  const size_t O_PRB    = 61363008;   // 12,544
  const size_t O_DIST   = 61375552;   // 32
  const size_t O_KEPT   = 61375584;   // 6,336 ints
  const size_t O_ELIM   = 61381920;   // 6,272 ints
  const size_t O_TSK    = 61388192;   // 6,336
  const size_t O_TSE    = 61394528;   // 6,272
  const size_t O_THR    = 61400800;   // 768
  const size_t O_TSN    = 61401568;   // 6,336
  const size_t O_PART   = 61407904;   // 76,032; end = 61,483,936
  // aliases:
  const size_t O_H1    = O_ATTNR;
  const size_t O_ATTN  = O_ATTNR;
  const size_t O_AOUT  = O_QK;
  const size_t O_XRES  = O_QK + 9682944;
  const size_t O_H2    = O_QK;
  const size_t O_WBUF  = O_V;
  const size_t O_XPROP = O_ATTNR;
  const size_t O_XOUT  = O_ATTNR + 4866048;
  const size_t O_HBUF  = O_ATTNR + 9732096;

  const dim3 B256(256);
  const dim3 B128(128);

  // init pagerank state (ws is poisoned each launch)
  hipLaunchKernelGGL(init_pr, dim3(49), B256, 0, stream, ws + O_PRA, ws + O_DIST);

  // LN1
  hipLaunchKernelGGL(ln_kernel, dim3(12608), B256, 0, stream, x, ln1_g, ln1_b, ws + O_H1);
  // QK = h1 @ w_qkv[0:1536]^T   [12608, 1536]
  hipLaunchKernelGGL(gemm_bias_act, dim3(197, 12), B128, 0, stream,
                     ws + O_H1, 768, w_qkv, 768, (const float*)nullptr,
                     (const float*)nullptr, ws + O_QK, 1536, 768, 0);
  // V = h1 @ w_qkv[1536:2304]^T   [12608, 768]
  hipLaunchKernelGGL(gemm_bias_act, dim3(197, 6), B128, 0, stream,
                     ws + O_H1, 768, w_qkv + (size_t)1536 * 768, 768,
                     (const float*)nullptr, (const float*)nullptr,
                     ws + O_V, 768, 768, 0);
  // logits
  hipLaunchKernelGGL(qk_kernel, dim3(4, 2, 768), B256, 0, stream, ws + O_QK, ws + O_ATTN);
  // fused softmax + head-mean + rowsum
  hipLaunchKernelGGL(softmax_fused, dim3(12608), B256, 0, stream,
                     ws + O_ATTN, ts, ws + O_WM, ws + O_ROWSUM);
  // attn @ V  (writes AOUT over the dead QK region)
  hipLaunchKernelGGL(av_kernel, dim3(4, 768), B256, 0, stream, ws + O_V, ws + O_ATTN, ws + O_AOUT);
  // proj + bias + residual(x)
  hipLaunchKernelGGL(gemm_bias_act, dim3(197, 6), B128, 0, stream,
                     ws + O_AOUT, 768, w_proj, 768, b_proj, x, ws + O_XRES, 768, 768, 0);

  // pagerank: 20 chained iterations (2 blocks/batch) with device-side skip
  for (int j = 0; j < 20; ++j) {
    const float* pin = ws + ((j & 1) ? O_PRB : O_PRA);
    float* pout      = ws + ((j & 1) ? O_PRA : O_PRB);
    hipLaunchKernelGGL(pagerank_iter, dim3(64, 2), B128, 0, stream,
                       ws + O_WM, ws + O_ROWSUM, pin, pout, ws + O_DIST, j);
  }
  // final pr in O_PRA (20 iterations -> even count -> result back in A)

  hipLaunchKernelGGL(select_kernel, dim3(64), B256, 0, stream,
                     ws + O_PRA, ts, (int*)(ws + O_KEPT), (int*)(ws + O_ELIM),
                     ws + O_TSK, ws + O_TSE);
  hipLaunchKernelGGL(gather_w, dim3(38, 768), B256, 0, stream,
                     ws + O_ATTN, (const int*)(ws + O_KEPT), (const int*)(ws + O_ELIM),
                     ws + O_WBUF);
  hipLaunchKernelGGL(thresh_kernel, dim3(768), B256, 0, stream, ws + O_WBUF, ws + O_THR);
  hipLaunchKernelGGL(xprop_kernel, dim3(768), B256, 0, stream,
                     ws + O_XRES, ws + O_WBUF, ws + O_THR, (const int*)(ws + O_ELIM),
                     ws + O_TSE, ws + O_XPROP, ws + O_PART);
  hipLaunchKernelGGL(tsfinal_kernel, dim3(25), B256, 0, stream,
                     ws + O_PART, ws + O_TSK, ws + O_TSN, out + 4866048);
  // fused combine + LN2
  hipLaunchKernelGGL(combine_ln_kernel, dim3(6336), B256, 0, stream,
                     ws + O_XRES, ws + O_XPROP, (const int*)(ws + O_KEPT),
                     ws + O_TSK, ws + O_TSN, ln2_g, ln2_b,
                     ws + O_XOUT, ws + O_H2);

  // MLP
  hipLaunchKernelGGL(gemm_bias_act, dim3(99, 24), B128, 0, stream,
                     ws + O_H2, 768, w_fc1, 768, b_fc1, (const float*)nullptr,
                     ws + O_HBUF, 3072, 768, 1);
  hipLaunchKernelGGL(gemm_bias_act, dim3(99, 6), B128, 0, stream,
                     ws + O_HBUF, 3072, w_fc2, 3072, b_fc2, ws + O_XOUT,
                     out, 768, 3072, 0);

  (void)in_sizes; (void)n_in; (void)out_size; (void)ws_size;
}

// Round 8
// 2360.656 us; speedup vs baseline: 1.3707x; 1.3707x over previous
//
#include <hip/hip_runtime.h>
#include <cstddef>
#include <cstdint>

// ============================================================================
// GraphPropagationBlock on MI355X — all-fp32 implementation (round 8).
// Round-7 counters: gemm 862us, VALUBusy 26%, Occupancy 7%, VGPR 132 ->
// latency-bound from low occupancy (2-3 waves/SIMD). Round-8 delta: GEMM
// per-thread tile 8x8/128thr -> 4x8/256thr (VGPR ~75 -> 4+ waves/SIMD),
// same BM64/BN128/BK16 double-buffer + conflict-free split fragments.
// Attention/pagerank path stays fp32 (argsort discontinuity).
// ============================================================================

#define DEV_INLINE __device__ __forceinline__

DEV_INLINE float waveReduceSum(float v) {
#pragma unroll
  for (int off = 32; off > 0; off >>= 1) v += __shfl_xor(v, off, 64);
  return v;
}
DEV_INLINE float waveReduceMax(float v) {
#pragma unroll
  for (int off = 32; off > 0; off >>= 1) v = fmaxf(v, __shfl_xor(v, off, 64));
  return v;
}
DEV_INLINE int clampi(int v, int lo, int hi) { return v < lo ? lo : (v > hi ? hi : v); }

// ---------------------------------------------------------------------------
// LayerNorm over C=768, one block (256 thr) per row, 3 elems/thread. (LN1)
// ---------------------------------------------------------------------------
__global__ __launch_bounds__(256) void ln_kernel(
    const float* __restrict__ x, const float* __restrict__ g,
    const float* __restrict__ bb, float* __restrict__ y)
{
  const int row = blockIdx.x;
  const int t = threadIdx.x;
  const float* xr = x + (size_t)row * 768;
  float* yr = y + (size_t)row * 768;
  float v0 = xr[t], v1 = xr[t + 256], v2 = xr[t + 512];
  __shared__ float red[8];
  const int wid = t >> 6, lane = t & 63;
  float s = v0 + v1 + v2;
  s = waveReduceSum(s);
  if (lane == 0) red[wid] = s;
  __syncthreads();
  if (t == 0) red[4] = (red[0] + red[1] + red[2] + red[3]) * (1.f / 768.f);
  __syncthreads();
  const float mu = red[4];
  float d0 = v0 - mu, d1 = v1 - mu, d2 = v2 - mu;
  float q = d0 * d0 + d1 * d1 + d2 * d2;
  q = waveReduceSum(q);
  if (lane == 0) red[wid] = q;
  __syncthreads();
  if (t == 0) red[5] = 1.0f / sqrtf((red[0] + red[1] + red[2] + red[3]) * (1.f / 768.f) + 1e-5f);
  __syncthreads();
  const float rs = red[5];
  yr[t]       = d0 * rs * g[t]       + bb[t];
  yr[t + 256] = d1 * rs * g[t + 256] + bb[t + 256];
  yr[t + 512] = d2 * rs * g[t + 512] + bb[t + 512];
}

// ---------------------------------------------------------------------------
// Generic fp32 GEMM: C[M,N] = A[M,K] @ B[N,K]^T (+bias) (+GELU) (+residual).
// BM=64, BN=128, BK=16; 256 threads; 4x8 per thread (rows r0..r0+3, cols
// {c0..c0+3, c0+64..c0+67}); double-buffered LDS. VGPR ~75 -> 4+ waves/SIMD
// (round-8 occupancy fix vs 8x8/132-VGPR/2-waves). All fragment reads are
// 16B-stride (2 lanes/bank = free); staging writes 2-way (free).
// Requires M%64==0, N%128==0, K%16==0 (true for all call sites).
// grid = (M/64, N/128), block 256.
// ---------------------------------------------------------------------------
__global__ __launch_bounds__(256) void gemm_bias_act(
    const float* __restrict__ A, int lda,
    const float* __restrict__ B, int ldb,
    const float* __restrict__ bias,   // may be null
    const float* __restrict__ res,    // may be null (same layout as C)
    float* __restrict__ C, int ldc,
    int K, int act)
{
  __shared__ float As[2][16][68];   // [buf][k][m]
  __shared__ float Bs[2][16][132];  // [buf][k][n]
  const int t = threadIdx.x;
  const int m0 = blockIdx.x * 64;
  const int n0 = blockIdx.y * 128;

  // staging: A 64x16 -> thread t loads float4 at row t>>2, k (t&3)*4
  //          B 128x16 -> thread t loads 2 float4 at row t>>1, k (t&1)*8
  const int sar = t >> 2, sak = (t & 3) << 2;
  const int sbr = t >> 1, sbk = (t & 1) << 3;
  const float* Aptr = A + (size_t)(m0 + sar) * lda + sak;
  const float* Bptr = B + (size_t)(n0 + sbr) * ldb + sbk;

  const int r0 = (t >> 4) << 2;   // 0..60
  const int c0 = (t & 15) << 2;   // 0..60

  float acc[4][8];
#pragma unroll
  for (int i = 0; i < 4; ++i)
#pragma unroll
    for (int j = 0; j < 8; ++j) acc[i][j] = 0.f;

  float4 a0 = *(const float4*)(Aptr);
  float4 b0 = *(const float4*)(Bptr);
  float4 b1 = *(const float4*)(Bptr + 4);

  int buf = 0;
  for (int k0 = 0; k0 < K; k0 += 16) {
    As[buf][sak + 0][sar] = a0.x; As[buf][sak + 1][sar] = a0.y;
    As[buf][sak + 2][sar] = a0.z; As[buf][sak + 3][sar] = a0.w;
    Bs[buf][sbk + 0][sbr] = b0.x; Bs[buf][sbk + 1][sbr] = b0.y;
    Bs[buf][sbk + 2][sbr] = b0.z; Bs[buf][sbk + 3][sbr] = b0.w;
    Bs[buf][sbk + 4][sbr] = b1.x; Bs[buf][sbk + 5][sbr] = b1.y;
    Bs[buf][sbk + 6][sbr] = b1.z; Bs[buf][sbk + 7][sbr] = b1.w;
    __syncthreads();
    if (k0 + 16 < K) {  // prefetch next slab; latency hides under compute
      a0 = *(const float4*)(Aptr + k0 + 16);
      b0 = *(const float4*)(Bptr + k0 + 16);
      b1 = *(const float4*)(Bptr + k0 + 20);
    }
#pragma unroll
    for (int kk = 0; kk < 16; ++kk) {
      float4 av  = *(const float4*)&As[buf][kk][r0];
      float4 bv0 = *(const float4*)&Bs[buf][kk][c0];
      float4 bv1 = *(const float4*)&Bs[buf][kk][c0 + 64];
      float ar[4] = {av.x, av.y, av.z, av.w};
      float br[8] = {bv0.x, bv0.y, bv0.z, bv0.w, bv1.x, bv1.y, bv1.z, bv1.w};
#pragma unroll
      for (int i = 0; i < 4; ++i)
#pragma unroll
        for (int j = 0; j < 8; ++j) acc[i][j] = fmaf(ar[i], br[j], acc[i][j]);
    }
    buf ^= 1;
  }

#pragma unroll
  for (int i = 0; i < 4; ++i) {
    const int m = m0 + r0 + i;
    float* Crow = C + (size_t)m * ldc + n0;
    const float* Rrow = res ? res + (size_t)m * ldc + n0 : nullptr;
#pragma unroll
    for (int j = 0; j < 8; ++j) {
      const int n = (j < 4) ? (c0 + j) : (64 + c0 + j - 4);
      float v = acc[i][j];
      if (bias) v += bias[n0 + n];
      if (act == 1) v = 0.5f * v * (1.f + erff(v * 0.70710678118654752440f));
      if (Rrow) v += Rrow[n];
      Crow[n] = v;
    }
  }
}

// ---------------------------------------------------------------------------
// QK^T per (b,h): logits[n,m] = (0.125*q[n]) . k[m]. grid (4, 2, B*H).
// qk buffer layout: row (b*197+n), col = which*768 + h*64 + d, ld = 1536
// (which: 0=Q, 1=K). Split-fragment columns for conflict-free LDS.
// ---------------------------------------------------------------------------
__global__ __launch_bounds__(256) void qk_kernel(
    const float* __restrict__ qk, float* __restrict__ attn)
{
  const int bh = blockIdx.z;
  const int b = bh / 12, h = bh % 12;
  const int n0 = blockIdx.x * 64;
  const int m0 = blockIdx.y * 128;
  __shared__ float Qs[16][68];
  __shared__ float Ks[16][132];
  const int t = threadIdx.x;
  const int lr = t >> 2;
  const int lk = (t & 3) << 2;
  const float* base = qk + (size_t)b * 197 * 1536 + h * 64;
  float acc[4][8];
#pragma unroll
  for (int i = 0; i < 4; ++i)
#pragma unroll
    for (int j = 0; j < 8; ++j) acc[i][j] = 0.f;
  const int r0 = (t >> 4) << 2;
  const int c0 = (t & 15) << 2;

  for (int k0 = 0; k0 < 64; k0 += 16) {
    const int n = n0 + lr;
    float4 av = make_float4(0.f, 0.f, 0.f, 0.f);
    if (n < 197) av = *(const float4*)(base + (size_t)n * 1536 + k0 + lk);
    av.x *= 0.125f; av.y *= 0.125f; av.z *= 0.125f; av.w *= 0.125f;
    const int m1 = m0 + lr, m2 = m0 + 64 + lr;
    float4 bv0 = make_float4(0.f, 0.f, 0.f, 0.f);
    float4 bv1 = make_float4(0.f, 0.f, 0.f, 0.f);
    if (m1 < 197) bv0 = *(const float4*)(base + 768 + (size_t)m1 * 1536 + k0 + lk);
    if (m2 < 197) bv1 = *(const float4*)(base + 768 + (size_t)m2 * 1536 + k0 + lk);
    Qs[lk + 0][lr] = av.x;  Qs[lk + 1][lr] = av.y;
    Qs[lk + 2][lr] = av.z;  Qs[lk + 3][lr] = av.w;
    Ks[lk + 0][lr] = bv0.x; Ks[lk + 1][lr] = bv0.y;
    Ks[lk + 2][lr] = bv0.z; Ks[lk + 3][lr] = bv0.w;
    Ks[lk + 0][lr + 64] = bv1.x; Ks[lk + 1][lr + 64] = bv1.y;
    Ks[lk + 2][lr + 64] = bv1.z; Ks[lk + 3][lr + 64] = bv1.w;
    __syncthreads();
#pragma unroll
    for (int kk = 0; kk < 16; ++kk) {
      float4 a  = *(const float4*)&Qs[kk][r0];
      float4 b0 = *(const float4*)&Ks[kk][c0];
      float4 b1 = *(const float4*)&Ks[kk][c0 + 64];
      float ar[4] = {a.x, a.y, a.z, a.w};
      float br[8] = {b0.x, b0.y, b0.z, b0.w, b1.x, b1.y, b1.z, b1.w};
#pragma unroll
      for (int i = 0; i < 4; ++i)
#pragma unroll
        for (int j = 0; j < 8; ++j) acc[i][j] = fmaf(ar[i], br[j], acc[i][j]);
    }
    __syncthreads();
  }

  float* ab = attn + (size_t)bh * 38809;
#pragma unroll
  for (int i = 0; i < 4; ++i) {
    const int n = n0 + r0 + i;
    if (n >= 197) continue;
#pragma unroll
    for (int j = 0; j < 8; ++j) {
      const int m = m0 + ((j < 4) ? (c0 + j) : (64 + c0 + j - 4));
      if (m < 197) ab[(size_t)n * 197 + m] = acc[i][j];
    }
  }
}

// ---------------------------------------------------------------------------
// Fused softmax (+log token_scales bias) + head-mean + rowsum.
// One block per (b,n): wave wid handles heads {wid, wid+4, wid+8}.
// Writes attn in place, wm[b,n,:], rowsum[b,n-1] = sum_{m>=1} wm.
// grid = B*197 = 12608 blocks, 256 threads.
// ---------------------------------------------------------------------------
__global__ __launch_bounds__(256) void softmax_fused(
    float* __restrict__ attn, const float* __restrict__ ts,
    float* __restrict__ wm, float* __restrict__ rowsum)
{
  const int bn = blockIdx.x;
  const int b = bn / 197, n = bn % 197;
  const int t = threadIdx.x;
  const int wid = t >> 6, lane = t & 63;
  __shared__ float colbuf[200];     // logts, then reused for wm row
  __shared__ float hsum[4][200];
  if (t < 197) colbuf[t] = logf(ts[b * 197 + t]);
  __syncthreads();

  int mm[4]; bool val[4];
#pragma unroll
  for (int i = 0; i < 4; ++i) { mm[i] = lane + 64 * i; val[i] = mm[i] < 197; }
  float lts[4];
#pragma unroll
  for (int i = 0; i < 4; ++i) lts[i] = val[i] ? colbuf[mm[i]] : 0.f;

  float macc[4] = {0.f, 0.f, 0.f, 0.f};
  for (int hi = 0; hi < 3; ++hi) {
    const int h = wid + 4 * hi;
    float* p = attn + ((size_t)(b * 12 + h) * 197 + n) * 197;
    float v[4];
#pragma unroll
    for (int i = 0; i < 4; ++i)
      v[i] = val[i] ? p[mm[i]] + lts[i] : -3.4e38f;
    float mx = waveReduceMax(fmaxf(fmaxf(v[0], v[1]), fmaxf(v[2], v[3])));
    float e[4]; float s = 0.f;
#pragma unroll
    for (int i = 0; i < 4; ++i) { e[i] = val[i] ? expf(v[i] - mx) : 0.f; s += e[i]; }
    s = waveReduceSum(s);
    const float inv = 1.f / s;
#pragma unroll
    for (int i = 0; i < 4; ++i) {
      if (val[i]) { const float a = e[i] * inv; p[mm[i]] = a; macc[i] += a; }
    }
  }
#pragma unroll
  for (int i = 0; i < 4; ++i) if (val[i]) hsum[wid][mm[i]] = macc[i];
  __syncthreads();
  if (t < 197) {
    const float wmv = (hsum[0][t] + hsum[1][t] + hsum[2][t] + hsum[3][t]) * (1.f / 12.f);
    wm[(size_t)b * 38809 + (size_t)n * 197 + t] = wmv;
    colbuf[t] = wmv;
  }
  __syncthreads();
  if (n >= 1 && wid == 0) {
    float s = colbuf[1 + lane] + colbuf[65 + lane] + colbuf[129 + lane];
    if (lane < 4) s += colbuf[193 + lane];
    s = waveReduceSum(s);
    if (lane == 0) rowsum[b * 196 + (n - 1)] = s;
  }
}

// ---------------------------------------------------------------------------
// attn @ V per (b,h): out[n,d] written into [B,N,C] at col h*64+d.
// V buffer: [B*197, 768] (col h*64+d). grid (4, B*H). BM=64 x BN=64, BK=16.
// ---------------------------------------------------------------------------
__global__ __launch_bounds__(256) void av_kernel(
    const float* __restrict__ v, const float* __restrict__ attn,
    float* __restrict__ aout)
{
  const int bh = blockIdx.y;
  const int b = bh / 12, h = bh % 12;
  const int n0 = blockIdx.x * 64;
  __shared__ float Ps[16][68];
  __shared__ float Vs[16][68];
  const int t = threadIdx.x;
  const float* ab = attn + (size_t)bh * 38809;
  const float* vbase = v + (size_t)b * 197 * 768 + h * 64;
  float acc[4][4];
#pragma unroll
  for (int i = 0; i < 4; ++i)
#pragma unroll
    for (int j = 0; j < 4; ++j) acc[i][j] = 0.f;
  const int r0 = (t >> 4) << 2;  // n
  const int c0 = (t & 15) << 2;  // d

  for (int k0 = 0; k0 < 197; k0 += 16) {
    {
      const int kk = t & 15;
      const int nb = t >> 4;
#pragma unroll
      for (int s = 0; s < 4; ++s) {
        const int n = nb + 16 * s;
        const int gn = n0 + n, gk = k0 + kk;
        float vv = 0.f;
        if (gn < 197 && gk < 197) vv = ab[(size_t)gn * 197 + gk];
        Ps[kk][n] = vv;
      }
      const int d = t & 63;
      const int kb = t >> 6;
#pragma unroll
      for (int s = 0; s < 4; ++s) {
        const int kk2 = kb + 4 * s;
        const int gk = k0 + kk2;
        float vv = 0.f;
        if (gk < 197) vv = vbase[(size_t)gk * 768 + d];
        Vs[kk2][d] = vv;
      }
    }
    __syncthreads();
#pragma unroll
    for (int kk = 0; kk < 16; ++kk) {
      float4 a = *(const float4*)&Ps[kk][r0];
      float4 bv = *(const float4*)&Vs[kk][c0];
      float ar[4] = {a.x, a.y, a.z, a.w};
      float br[4] = {bv.x, bv.y, bv.z, bv.w};
#pragma unroll
      for (int i = 0; i < 4; ++i)
#pragma unroll
        for (int j = 0; j < 4; ++j) acc[i][j] = fmaf(ar[i], br[j], acc[i][j]);
    }
    __syncthreads();
  }

#pragma unroll
  for (int i = 0; i < 4; ++i) {
    const int n = n0 + r0 + i;
    if (n >= 197) continue;
#pragma unroll
    for (int j = 0; j < 4; ++j)
      aout[((size_t)b * 197 + n) * 768 + h * 64 + c0 + j] = acc[i][j];
  }
}

// init pr0 = 1/196 and dist2[0..19] = 0
__global__ __launch_bounds__(256) void init_pr(
    float* __restrict__ prA, float* __restrict__ dist2)
{
  const int i = blockIdx.x * 256 + threadIdx.x;
  if (i < 12544) prA[i] = 1.f / 196.f;
  if (i < 20) dist2[i] = 0.f;
}

// one pagerank iteration, split 2 blocks per batch: grid (64, 2) x 128 thr.
// Block (b,half) computes output rows half*98..half*98+97. Kernel j skips
// (copying its rows) iff dist2[j-1] < 1e-6 (while cond: dist >= 1e-3).
__global__ __launch_bounds__(128) void pagerank_iter(
    const float* __restrict__ wm, const float* __restrict__ rowsum,
    const float* __restrict__ prIn, float* __restrict__ prOut,
    float* __restrict__ dist2, int j)
{
  const int b = blockIdx.x, half = blockIdx.y, t = threadIdx.x;
  const int row = half * 98 + t;  // t < 98 active
  if (j > 0 && dist2[j - 1] < 1e-6f) {
    if (t < 98) prOut[b * 196 + row] = prIn[b * 196 + row];
    return;
  }
  __shared__ float u[196];
  for (int i = t; i < 196; i += 128) u[i] = prIn[b * 196 + i] / rowsum[b * 196 + i];
  __syncthreads();
  float d2 = 0.f;
  if (t < 98) {
    const float* base = wm + (size_t)b * 38809 + 1 + row;
    float a0 = 0.f, a1 = 0.f, a2 = 0.f, a3 = 0.f;
    for (int c = 0; c < 196; c += 4) {
      a0 = fmaf(base[(size_t)(1 + c) * 197], u[c], a0);
      a1 = fmaf(base[(size_t)(2 + c) * 197], u[c + 1], a1);
      a2 = fmaf(base[(size_t)(3 + c) * 197], u[c + 2], a2);
      a3 = fmaf(base[(size_t)(4 + c) * 197], u[c + 3], a3);
    }
    const float acc = (a0 + a1) + (a2 + a3);
    const float nw = 0.95f * acc + (0.05f / 196.f);
    const float d = nw - prIn[b * 196 + row];
    d2 = d * d;
    prOut[b * 196 + row] = nw;
  }
  d2 = waveReduceSum(d2);
  __shared__ float red[2];
  if ((t & 63) == 0) red[t >> 6] = d2;
  __syncthreads();
  if (t == 0) atomicAdd(&dist2[j], red[0] + red[1]);
}

// ---------------------------------------------------------------------------
// Selection: stable descending argsort by rank counting; build sorted
// kept (CLS + top98 tokens, ascending) and elim lists + gathered scales.
// Writes are clamped (defensive: pathological pr -> wrong answer, not OOB).
// ---------------------------------------------------------------------------
__global__ __launch_bounds__(256) void select_kernel(
    const float* __restrict__ pr, const float* __restrict__ ts,
    int* __restrict__ kept, int* __restrict__ elim,
    float* __restrict__ tsk, float* __restrict__ tse)
{
  const int b = blockIdx.x, t = threadIdx.x;
  __shared__ float v[196];
  __shared__ unsigned char kf[196];
  if (t < 196) v[t] = pr[b * 196 + t];
  __syncthreads();
  if (t < 196) {
    const float vt = v[t];
    int rank = 0;
    for (int j = 0; j < 196; ++j) {
      const float vj = v[j];
      rank += (vj > vt) || (vj == vt && j < t);
    }
    kf[t] = (rank < 98) ? 1 : 0;
  }
  __syncthreads();
  if (t < 196) {
    int pos = 0;
    for (int j = 0; j < t; ++j) pos += kf[j];
    const int tok = t + 1;
    if (kf[t]) {
      const int p2 = clampi(pos, 0, 97);
      kept[b * 99 + 1 + p2] = tok;
      tsk[b * 99 + 1 + p2] = ts[b * 197 + tok];
    } else {
      const int e2 = clampi(t - pos, 0, 97);
      elim[b * 98 + e2] = tok;
      tse[b * 98 + e2] = ts[b * 197 + tok];
    }
  }
  if (t == 0) { kept[b * 99] = 0; tsk[b * 99] = ts[b * 197]; }
}

// gather w[b,h,k,e] = attn[b,h,kept[k],elim[e]]  grid (38, B*H)
__global__ __launch_bounds__(256) void gather_w(
    const float* __restrict__ attn, const int* __restrict__ kept,
    const int* __restrict__ elim, float* __restrict__ wbuf)
{
  const int bh = blockIdx.y;
  const int b = bh / 12;
  const float* ab = attn + (size_t)bh * 38809;
  const int* kb = kept + b * 99;
  const int* eb = elim + b * 98;
  float* wb = wbuf + (size_t)bh * 9702;
  const int i = blockIdx.x * 256 + threadIdx.x;
  if (i < 9702) {
    const int k = i / 98, e = i % 98;
    const int kt = clampi(kb[k], 0, 196);
    const int et = clampi(eb[e], 0, 196);
    wb[i] = ab[(size_t)kt * 197 + et];
  }
}

// per-(b,h) kth-largest (kth = int(9702*0.2)=1940, 0-indexed desc) via
// 4-pass radix select on positive-float bits. grid B*H blocks.
__global__ __launch_bounds__(256) void thresh_kernel(
    const float* __restrict__ wbuf, float* __restrict__ thr)
{
  const int bh = blockIdx.x, t = threadIdx.x;
  const float* wb = wbuf + (size_t)bh * 9702;
  __shared__ unsigned hist[256];
  __shared__ unsigned s_prefix;
  __shared__ int s_k;
  if (t == 0) { s_prefix = 0u; s_k = 1940; }
  for (int pass = 0; pass < 4; ++pass) {
    const int shift = 24 - 8 * pass;
    hist[t] = 0u;
    __syncthreads();
    const unsigned pref = s_prefix;
    for (int i = t; i < 9702; i += 256) {
      const unsigned u = __float_as_uint(wb[i]);
      const bool match = (pass == 0) || ((u >> (shift + 8)) == (pref >> (shift + 8)));
      if (match) atomicAdd(&hist[(u >> shift) & 255u], 1u);
    }
    __syncthreads();
    if (t == 0) {
      int k = s_k;
      int sel = 0;
      for (int bin = 255; bin >= 0; --bin) {
        const int c = (int)hist[bin];
        if (k < c) { sel = bin; break; }
        k -= c;
      }
      s_prefix |= ((unsigned)sel << shift);
      s_k = k;
    }
    __syncthreads();
  }
  if (t == 0) thr[bh] = __uint_as_float(s_prefix);
}

// x_prop[b,k,h*64+d] = sum_e wsp[k,e] * (x_res[b,elim[e],h*64+d]*tse[e])
// Also emits partial[bh*99+k] = sum_e wsp[k,e]*tse[e] (lane d==0 writes).
// grid B*H blocks, 256 thr (d = t&63, row group r = t>>6).
__global__ __launch_bounds__(256) void xprop_kernel(
    const float* __restrict__ xres, const float* __restrict__ wbuf,
    const float* __restrict__ thr, const int* __restrict__ elim,
    const float* __restrict__ tse, float* __restrict__ xprop,
    float* __restrict__ partial)
{
  const int bh = blockIdx.x;
  const int b = bh / 12, h = bh % 12;
  __shared__ float xe[98][68];
  __shared__ float tsew[98];
  const int t = threadIdx.x;
  const int d = t & 63, r = t >> 6;
  if (t < 98) tsew[t] = tse[b * 98 + t];
  for (int e = r; e < 98; e += 4) {
    const int tok = clampi(elim[b * 98 + e], 0, 196);
    xe[e][d] = xres[((size_t)b * 197 + tok) * 768 + h * 64 + d] * tse[b * 98 + e];
  }
  __syncthreads();
  const float th = thr[bh];
  const float* wb = wbuf + (size_t)bh * 9702;
  for (int k = r; k < 99; k += 4) {
    const float* wr = wb + k * 98;
    float acc = 0.f;
    float ssum = 0.f;
    for (int e = 0; e < 98; ++e) {
      float w = wr[e];
      w = (w >= th) ? w : 0.f;
      acc = fmaf(w, xe[e][d], acc);
      ssum = fmaf(w, tsew[e], ssum);
    }
    xprop[((size_t)b * 99 + k) * 768 + h * 64 + d] = acc;
    if (d == 0) partial[(size_t)bh * 99 + k] = ssum;
  }
}

// tsn[b,k] = tsk[b,k] + (1/12) sum_h partial[(b*12+h)*99+k]; writes out_ts.
// grid 25 x 256 (6336 items).
__global__ __launch_bounds__(256) void tsfinal_kernel(
    const float* __restrict__ partial, const float* __restrict__ tsk,
    float* __restrict__ tsn, float* __restrict__ out_ts)
{
  const int i = blockIdx.x * 256 + threadIdx.x;
  if (i >= 6336) return;
  const int b = i / 99, k = i % 99;
  float acc = 0.f;
#pragma unroll
  for (int h = 0; h < 12; ++h) acc += partial[(size_t)(b * 12 + h) * 99 + k];
  const float v = tsk[i] + acc * (1.f / 12.f);
  tsn[i] = v;
  out_ts[i] = v;
}

// ---------------------------------------------------------------------------
// Fused combine + LN2: per row bk, v = (x_res[kept]*tsk + xprop)/tsn is
// written to xout (needed for final residual) and layer-normed into y.
// grid 6336 blocks x 256 thr (3 elems/thread).
// ---------------------------------------------------------------------------
__global__ __launch_bounds__(256) void combine_ln_kernel(
    const float* __restrict__ xres, const float* __restrict__ xprop,
    const int* __restrict__ kept, const float* __restrict__ tsk,
    const float* __restrict__ tsn, const float* __restrict__ g,
    const float* __restrict__ bb, float* __restrict__ xout,
    float* __restrict__ y)
{
  const int bk = blockIdx.x;
  const int b = bk / 99;
  const int t = threadIdx.x;
  const int tok = clampi(kept[bk], 0, 196);
  const float sk = tsk[bk];
  const float sn = tsn[bk];
  const float* xr = xres + ((size_t)b * 197 + tok) * 768;
  const float* xp = xprop + (size_t)bk * 768;
  float v0 = (xr[t] * sk + xp[t]) / sn;
  float v1 = (xr[t + 256] * sk + xp[t + 256]) / sn;
  float v2 = (xr[t + 512] * sk + xp[t + 512]) / sn;
  float* xo = xout + (size_t)bk * 768;
  xo[t] = v0; xo[t + 256] = v1; xo[t + 512] = v2;

  __shared__ float red[8];
  const int wid = t >> 6, lane = t & 63;
  float s = v0 + v1 + v2;
  s = waveReduceSum(s);
  if (lane == 0) red[wid] = s;
  __syncthreads();
  if (t == 0) red[4] = (red[0] + red[1] + red[2] + red[3]) * (1.f / 768.f);
  __syncthreads();
  const float mu = red[4];
  float d0 = v0 - mu, d1 = v1 - mu, d2 = v2 - mu;
  float q = d0 * d0 + d1 * d1 + d2 * d2;
  q = waveReduceSum(q);
  if (lane == 0) red[wid] = q;
  __syncthreads();
  if (t == 0) red[5] = 1.0f / sqrtf((red[0] + red[1] + red[2] + red[3]) * (1.f / 768.f) + 1e-5f);
  __syncthreads();
  const float rs = red[5];
  float* yr = y + (size_t)bk * 768;
  yr[t]       = d0 * rs * g[t]       + bb[t];
  yr[t + 256] = d1 * rs * g[t + 256] + bb[t + 256];
  yr[t + 512] = d2 * rs * g[t + 512] + bb[t + 512];
}

// ============================================================================
extern "C" void kernel_launch(void* const* d_in, const int* in_sizes, int n_in,
                              void* d_out, int out_size, void* d_ws, size_t ws_size,
                              hipStream_t stream)
{
  const float* x      = (const float*)d_in[0];
  const float* ts     = (const float*)d_in[1];
  const float* w_qkv  = (const float*)d_in[2];
  const float* w_proj = (const float*)d_in[3];
  const float* b_proj = (const float*)d_in[4];
  const float* ln1_g  = (const float*)d_in[5];
  const float* ln1_b  = (const float*)d_in[6];
  const float* ln2_g  = (const float*)d_in[7];
  const float* ln2_b  = (const float*)d_in[8];
  const float* w_fc1  = (const float*)d_in[9];
  const float* b_fc1  = (const float*)d_in[10];
  const float* w_fc2  = (const float*)d_in[11];
  const float* b_fc2  = (const float*)d_in[12];
  float* out = (float*)d_out;
  float* ws  = (float*)d_ws;

  // -------- workspace layout: 61,483,936 floats = 234.6 MiB --------
  // R_QK   [19,365,888]: QK (qkvGEMM->qk_kernel); then AOUT@+0 (av->proj),
  //                      XRES@+9,682,944 (proj->xprop/combine), H2@+0
  //                      (combine_ln->fc1; disjoint from live XRES).
  // R_V    [ 9,682,944]: V (qkvGEMM->av); then WBUF@+0 (gather->xprop).
  // R_ATTN [29,805,312]: H1@+0 (ln1->qkvGEMMs); ATTN (qk->gather_w); then
  //                      XPROP@+0, XOUT@+4,866,048, HBUF@+9,732,096.
  // R_WM   [ 2,483,776]: head-mean (softmax_fused->pagerank).
  const size_t O_QK     = 0;
  const size_t O_V      = 19365888;
  const size_t O_ATTNR  = 29048832;
  const size_t O_WM     = 58854144;
  const size_t O_ROWSUM = 61337920;   // 12,544
  const size_t O_PRA    = 61350464;   // 12,544
  const size_t O_PRB    = 61363008;   // 12,544
  const size_t O_DIST   = 61375552;   // 32
  const size_t O_KEPT   = 61375584;   // 6,336 ints
  const size_t O_ELIM   = 61381920;   // 6,272 ints
  const size_t O_TSK    = 61388192;   // 6,336
  const size_t O_TSE    = 61394528;   // 6,272
  const size_t O_THR    = 61400800;   // 768
  const size_t O_TSN    = 61401568;   // 6,336
  const size_t O_PART   = 61407904;   // 76,032; end = 61,483,936
  // aliases:
  const size_t O_H1    = O_ATTNR;
  const size_t O_ATTN  = O_ATTNR;
  const size_t O_AOUT  = O_QK;
  const size_t O_XRES  = O_QK + 9682944;
  const size_t O_H2    = O_QK;
  const size_t O_WBUF  = O_V;
  const size_t O_XPROP = O_ATTNR;
  const size_t O_XOUT  = O_ATTNR + 4866048;
  const size_t O_HBUF  = O_ATTNR + 9732096;

  const dim3 B256(256);
  const dim3 B128(128);

  // init pagerank state (ws is poisoned each launch)
  hipLaunchKernelGGL(init_pr, dim3(49), B256, 0, stream, ws + O_PRA, ws + O_DIST);

  // LN1
  hipLaunchKernelGGL(ln_kernel, dim3(12608), B256, 0, stream, x, ln1_g, ln1_b, ws + O_H1);
  // QK = h1 @ w_qkv[0:1536]^T   [12608, 1536]
  hipLaunchKernelGGL(gemm_bias_act, dim3(197, 12), B256, 0, stream,
                     ws + O_H1, 768, w_qkv, 768, (const float*)nullptr,
                     (const float*)nullptr, ws + O_QK, 1536, 768, 0);
  // V = h1 @ w_qkv[1536:2304]^T   [12608, 768]
  hipLaunchKernelGGL(gemm_bias_act, dim3(197, 6), B256, 0, stream,
                     ws + O_H1, 768, w_qkv + (size_t)1536 * 768, 768,
                     (const float*)nullptr, (const float*)nullptr,
                     ws + O_V, 768, 768, 0);
  // logits
  hipLaunchKernelGGL(qk_kernel, dim3(4, 2, 768), B256, 0, stream, ws + O_QK, ws + O_ATTN);
  // fused softmax + head-mean + rowsum
  hipLaunchKernelGGL(softmax_fused, dim3(12608), B256, 0, stream,
                     ws + O_ATTN, ts, ws + O_WM, ws + O_ROWSUM);
  // attn @ V  (writes AOUT over the dead QK region)
  hipLaunchKernelGGL(av_kernel, dim3(4, 768), B256, 0, stream, ws + O_V, ws + O_ATTN, ws + O_AOUT);
  // proj + bias + residual(x)
  hipLaunchKernelGGL(gemm_bias_act, dim3(197, 6), B256, 0, stream,
                     ws + O_AOUT, 768, w_proj, 768, b_proj, x, ws + O_XRES, 768, 768, 0);

  // pagerank: 20 chained iterations (2 blocks/batch) with device-side skip
  for (int j = 0; j < 20; ++j) {
    const float* pin = ws + ((j & 1) ? O_PRB : O_PRA);
    float* pout      = ws + ((j & 1) ? O_PRA : O_PRB);
    hipLaunchKernelGGL(pagerank_iter, dim3(64, 2), B128, 0, stream,
                       ws + O_WM, ws + O_ROWSUM, pin, pout, ws + O_DIST, j);
  }
  // final pr in O_PRA (20 iterations -> even count -> result back in A)

  hipLaunchKernelGGL(select_kernel, dim3(64), B256, 0, stream,
                     ws + O_PRA, ts, (int*)(ws + O_KEPT), (int*)(ws + O_ELIM),
                     ws + O_TSK, ws + O_TSE);
  hipLaunchKernelGGL(gather_w, dim3(38, 768), B256, 0, stream,
                     ws + O_ATTN, (const int*)(ws + O_KEPT), (const int*)(ws + O_ELIM),
                     ws + O_WBUF);
  hipLaunchKernelGGL(thresh_kernel, dim3(768), B256, 0, stream, ws + O_WBUF, ws + O_THR);
  hipLaunchKernelGGL(xprop_kernel, dim3(768), B256, 0, stream,
                     ws + O_XRES, ws + O_WBUF, ws + O_THR, (const int*)(ws + O_ELIM),
                     ws + O_TSE, ws + O_XPROP, ws + O_PART);
  hipLaunchKernelGGL(tsfinal_kernel, dim3(25), B256, 0, stream,
                     ws + O_PART, ws + O_TSK, ws + O_TSN, out + 4866048);
  // fused combine + LN2
  hipLaunchKernelGGL(combine_ln_kernel, dim3(6336), B256, 0, stream,
                     ws + O_XRES, ws + O_XPROP, (const int*)(ws + O_KEPT),
                     ws + O_TSK, ws + O_TSN, ln2_g, ln2_b,
                     ws + O_XOUT, ws + O_H2);

  // MLP
  hipLaunchKernelGGL(gemm_bias_act, dim3(99, 24), B256, 0, stream,
                     ws + O_H2, 768, w_fc1, 768, b_fc1, (const float*)nullptr,
                     ws + O_HBUF, 3072, 768, 1);
  hipLaunchKernelGGL(gemm_bias_act, dim3(99, 6), B256, 0, stream,
                     ws + O_HBUF, 3072, w_fc2, 3072, b_fc2, ws + O_XOUT,
                     out, 768, 3072, 0);

  (void)in_sizes; (void)n_in; (void)out_size; (void)ws_size;
}